// Round 1
// baseline (241.559 us; speedup 1.0000x reference)
//
#include <hip/hip_runtime.h>
#include <math.h>

namespace {
constexpr int Bc = 16;     // batch
constexpr int DC = 16;     // deep channels
constexpr int ND = 1024;   // deep length
constexpr int C  = 64;     // c_in
constexpr int N  = 4096;   // sequence
constexpr int CO = 128;    // c_out
constexpr int KW = 7;
constexpr int F  = C * KW;   // 448
constexpr int LT = 32;       // l-tile for k2
constexpr int PHI_LD = 452;  // padded row: 452*4 % 16 == 0, 452 % 32 == 4

// K1: one block per (b,c). Fused interp + pointwise conv + mean/var + normalize.
__global__ __launch_bounds__(256)
void k1_pwconv_norm(const float* __restrict__ deep,
                    const float* __restrict__ conv_w,
                    const float* __restrict__ conv_b,
                    float* __restrict__ xs)
{
    const int blk = blockIdx.x;
    const int b = blk >> 6;
    const int c = blk & 63;
    float cw[DC];
#pragma unroll
    for (int d = 0; d < DC; ++d) cw[d] = conv_w[c * DC + d];  // uniform -> s_load
    const float cb = conv_b[c];
    const float* dp = deep + b * DC * ND;

    float yv[16];
    float s1 = 0.f, s2 = 0.f;
#pragma unroll 4
    for (int it = 0; it < 16; ++it) {
        const int j = threadIdx.x + 256 * it;
        float src = 0.25f * (float)j - 0.375f;
        src = fminf(fmaxf(src, 0.f), (float)(ND - 1));
        const int lo = (int)src;            // src >= 0, trunc == floor
        const int hi = min(lo + 1, ND - 1);
        const float w = src - (float)lo;
        float vlo = 0.f, vhi = 0.f;
#pragma unroll
        for (int d = 0; d < DC; ++d) {
            vlo = fmaf(dp[d * ND + lo], cw[d], vlo);
            vhi = fmaf(dp[d * ND + hi], cw[d], vhi);
        }
        const float y = vlo + (vhi - vlo) * w + cb;
        yv[it] = y;
        s1 += y;
        s2 = fmaf(y, y, s2);
    }
    __shared__ float r1[256];
    __shared__ float r2[256];
    r1[threadIdx.x] = s1;
    r2[threadIdx.x] = s2;
    __syncthreads();
    for (int off = 128; off > 0; off >>= 1) {
        if (threadIdx.x < off) {
            r1[threadIdx.x] += r1[threadIdx.x + off];
            r2[threadIdx.x] += r2[threadIdx.x + off];
        }
        __syncthreads();
    }
    const float mean = r1[0] * (1.f / N);
    const float var  = (r2[0] - (float)N * mean * mean) * (1.f / (N - 1)); // ddof=1
    const float s    = 0.5f / (var + 1e-9f);   // GAMA / (var + EPS)  (NOT rsqrt!)
    float* xsp = xs + (b * C + c) * N;
#pragma unroll 4
    for (int it = 0; it < 16; ++it) {
        const int j = threadIdx.x + 256 * it;
        xsp[j] = s * (yv[it] - mean);
    }
}

// K2: one block per (b, 32-wide l tile).
// Phase 1: phi[l][c*7+k] = alpha * sech^2(|xs_pad - xs_center|) * x_pad  (LDS)
// Phase 2: out[b,o,l] = sum_f phi[l][f] * fc_w[o][f], 4o x 4l register tile/thread
__global__ __launch_bounds__(256)
void k2_win_gemm(const float* __restrict__ xs,
                 const float* __restrict__ x,
                 const float* __restrict__ fcw,
                 float* __restrict__ out)
{
    __shared__ float phi[LT][PHI_LD];
    const int b   = blockIdx.y;
    const int l0  = blockIdx.x * LT;
    const int tid = threadIdx.x;

    // ---- phase 1 ----
#pragma unroll
    for (int pp = 0; pp < (LT * C) / 256; ++pp) {   // 8 (l,c) pairs per thread
        const int id = tid + 256 * pp;
        const int l = id & (LT - 1);
        const int c = id >> 5;                       // LT == 32
        const int gl = l0 + l;
        const float* xsp = xs + (b * C + c) * N;
        const float* xp  = x  + (b * C + c) * N;
        const float center = xsp[gl];                // == x1[...,M] (k=3 tap)
        float lossv[KW], xv[KW];
        float lsum = 0.f;
#pragma unroll
        for (int k = 0; k < KW; ++k) {
            int p = gl + k - 3;
            p = (p < 0) ? -p : ((p >= N) ? (2 * N - 2 - p) : p);  // reflect pad
            const float v = xsp[p];
            xv[k] = xp[p];
            const float d = fabsf(v - center);
            // 1 - tanh(d)^2 = 4 e^{-2d} / (1 + e^{-2d})^2, overflow-safe for d>=0
            const float e = __expf(-2.f * d);
            const float t = 1.f + e;
            const float lo = 4.f * e / (t * t);
            lossv[k] = lo;
            lsum += lo;
        }
        const float alpha = 1.f / lsum;
#pragma unroll
        for (int k = 0; k < KW; ++k)
            phi[l][c * KW + k] = lossv[k] * alpha * xv[k];
    }
    __syncthreads();

    // ---- phase 2 ----
    const int og = tid >> 3;   // 0..31 -> 4 output rows each
    const int lg = tid & 7;    // 0..7  -> 4 l each; lanes w/ same og store 128B contig
    const int o0 = og * 4;
    const int lt0 = lg * 4;
    float acc[4][4];
#pragma unroll
    for (int j = 0; j < 4; ++j)
#pragma unroll
        for (int i = 0; i < 4; ++i) acc[j][i] = 0.f;

    const float* w0 = fcw + o0 * F;
    for (int f = 0; f < F; f += 4) {     // 112 iters: 8x16B loads, 64 FMA
        float4 pv[4], wv[4];
#pragma unroll
        for (int i = 0; i < 4; ++i)
            pv[i] = *(const float4*)&phi[lt0 + i][f];
#pragma unroll
        for (int j = 0; j < 4; ++j)
            wv[j] = *(const float4*)&w0[j * F + f];
#pragma unroll
        for (int j = 0; j < 4; ++j)
#pragma unroll
            for (int i = 0; i < 4; ++i) {
                acc[j][i] = fmaf(wv[j].x, pv[i].x, acc[j][i]);
                acc[j][i] = fmaf(wv[j].y, pv[i].y, acc[j][i]);
                acc[j][i] = fmaf(wv[j].z, pv[i].z, acc[j][i]);
                acc[j][i] = fmaf(wv[j].w, pv[i].w, acc[j][i]);
            }
    }
#pragma unroll
    for (int j = 0; j < 4; ++j) {
        const int o = o0 + j;
        float4 r;
        r.x = acc[j][0]; r.y = acc[j][1]; r.z = acc[j][2]; r.w = acc[j][3];
        *(float4*)&out[(b * CO + o) * N + l0 + lt0] = r;
    }
}
} // namespace

extern "C" void kernel_launch(void* const* d_in, const int* in_sizes, int n_in,
                              void* d_out, int out_size, void* d_ws, size_t ws_size,
                              hipStream_t stream)
{
    const float* deep   = (const float*)d_in[0];
    const float* x      = (const float*)d_in[1];
    const float* conv_w = (const float*)d_in[2];
    const float* conv_b = (const float*)d_in[3];
    const float* fc_w   = (const float*)d_in[4];
    float* out = (float*)d_out;
    float* xs  = (float*)d_ws;   // 16*64*4096 floats = 16 MiB scratch

    hipLaunchKernelGGL(k1_pwconv_norm, dim3(Bc * C), dim3(256), 0, stream,
                       deep, conv_w, conv_b, xs);
    hipLaunchKernelGGL(k2_win_gemm, dim3(N / LT, Bc), dim3(256), 0, stream,
                       xs, x, fc_w, out);
}

// Round 2
// 123.773 us; speedup vs baseline: 1.9516x; 1.9516x over previous
//
#include <hip/hip_runtime.h>
#include <hip/hip_bf16.h>
#include <math.h>

namespace {
typedef __attribute__((ext_vector_type(8)))  short  short8;   // 8 bf16 = 4 VGPR (MFMA A/B frag)
typedef __attribute__((ext_vector_type(4)))  float  floatx4;  // MFMA C/D frag
typedef _Float16 f16;
typedef __attribute__((ext_vector_type(4)))  _Float16 half4;

constexpr int Bc = 16;    // batch
constexpr int DC = 16;    // deep channels
constexpr int ND = 1024;  // deep length
constexpr int C  = 64;    // c_in
constexpr int N  = 4096;  // sequence
constexpr int CO = 128;   // c_out
constexpr int KW = 7;
constexpr int F  = C * KW;     // 448
constexpr int LT = 32;         // l-tile in k2
constexpr int PLD = F + 8;     // 456 bf16/row: 912 B, 16B-aligned, stride 228 words == 4 mod 32

__device__ inline unsigned short f2bf(float f) {
    __hip_bfloat16 h = __float2bfloat16(f);      // RNE
    return __builtin_bit_cast(unsigned short, h);
}

// K1 blocks 0..1023: one per (b,c).
//   conv commutes with linear interp: V[t] = sum_d cw[d]*deep[d][t] (LDS, 4 KB),
//   then y(4t+r) = lerp of V[t-1],V[t],V[t+1] with fixed weights. mean/var, xs=fp16.
// K1 blocks 1024..1079: convert fc_w fp32 -> bf16 into ws (needed by k2).
__global__ __launch_bounds__(256)
void k1(const float* __restrict__ deep, const float* __restrict__ conv_w,
        const float* __restrict__ conv_b, const float* __restrict__ fcw,
        f16* __restrict__ xs, unsigned short* __restrict__ wb)
{
    if (blockIdx.x >= Bc * C) {                      // fc_w -> bf16, 56 blocks
        const int i = ((blockIdx.x - Bc * C) * 256 + threadIdx.x) * 4;  // < 57344
        const float4 v = *(const float4*)(fcw + i);
        ushort4 o;
        o.x = f2bf(v.x); o.y = f2bf(v.y); o.z = f2bf(v.z); o.w = f2bf(v.w);
        *(ushort4*)(wb + i) = o;
        return;
    }
    const int b = blockIdx.x >> 6;
    const int c = blockIdx.x & 63;
    const int tid = threadIdx.x;
    __shared__ float V[ND];
    __shared__ float r1[256], r2[256];

    float cw[DC];
#pragma unroll
    for (int d = 0; d < DC; ++d) cw[d] = conv_w[c * DC + d];   // uniform -> s_load
    const float cb = conv_b[c];
    const float* dp = deep + b * DC * ND;

#pragma unroll
    for (int p = 0; p < 4; ++p) {
        const int t = tid + 256 * p;
        float a = 0.f;
#pragma unroll
        for (int d = 0; d < DC; ++d) a = fmaf(dp[d * ND + t], cw[d], a);
        V[t] = a;
    }
    __syncthreads();

    float s1 = 0.f, s2 = 0.f;
#pragma unroll
    for (int it = 0; it < 4; ++it) {
        const int g = tid + 256 * it;
        const float vm = V[g == 0 ? 0 : g - 1];
        const float v0 = V[g];
        const float vp = V[g == ND - 1 ? ND - 1 : g + 1];
        const float y0 = fmaf(0.375f, vm, fmaf(0.625f, v0, cb));
        const float y1 = fmaf(0.125f, vm, fmaf(0.875f, v0, cb));
        const float y2 = fmaf(0.125f, vp, fmaf(0.875f, v0, cb));
        const float y3 = fmaf(0.375f, vp, fmaf(0.625f, v0, cb));
        s1 += (y0 + y1) + (y2 + y3);
        s2 = fmaf(y0, y0, s2); s2 = fmaf(y1, y1, s2);
        s2 = fmaf(y2, y2, s2); s2 = fmaf(y3, y3, s2);
    }
    r1[tid] = s1; r2[tid] = s2;
    __syncthreads();
    for (int off = 128; off > 0; off >>= 1) {
        if (tid < off) { r1[tid] += r1[tid + off]; r2[tid] += r2[tid + off]; }
        __syncthreads();
    }
    const float mean = r1[0] * (1.f / N);
    const float var  = (r2[0] - (float)N * mean * mean) * (1.f / (N - 1));  // ddof=1
    const float sc   = 0.5f / (var + 1e-9f);                                // GAMA/(var+EPS)

    f16* xsp = xs + (b * C + c) * N;
#pragma unroll
    for (int it = 0; it < 4; ++it) {
        const int g = tid + 256 * it;
        const float vm = V[g == 0 ? 0 : g - 1];
        const float v0 = V[g];
        const float vp = V[g == ND - 1 ? ND - 1 : g + 1];
        half4 h;
        h.x = (f16)((fmaf(0.375f, vm, fmaf(0.625f, v0, cb)) - mean) * sc);
        h.y = (f16)((fmaf(0.125f, vm, fmaf(0.875f, v0, cb)) - mean) * sc);
        h.z = (f16)((fmaf(0.125f, vp, fmaf(0.875f, v0, cb)) - mean) * sc);
        h.w = (f16)((fmaf(0.375f, vp, fmaf(0.625f, v0, cb)) - mean) * sc);
        *(half4*)(xsp + 4 * g) = h;
    }
}

// K2: one block per (b, 32-l tile).
// Phase 1: phi[l][c*7+k] = bf16( alpha * sech^2|xs_pad - xs_center| * x_pad )  (LDS)
// Phase 2: out[o,l] = sum_f w[o,f]*phi[l,f] via mfma_f32_16x16x32_bf16;
//          wave w owns o-stripe [32w,32w+32): 2x2 D-tiles of 16x16, K=448 in 14 steps.
__global__ __launch_bounds__(256)
void k2(const f16* __restrict__ xs, const float* __restrict__ x,
        const unsigned short* __restrict__ wb, float* __restrict__ out)
{
    __shared__ __align__(16) unsigned short phi[LT * PLD];
    const int b   = blockIdx.y;
    const int l0  = blockIdx.x * LT;
    const int tid = threadIdx.x;

    // ---- phase 1 ----
#pragma unroll
    for (int p = 0; p < (LT * C) / 256; ++p) {       // 8 (l,c) pairs/thread
        const int id = tid + 256 * p;
        const int l = id & (LT - 1);
        const int c = id >> 5;
        const int gl = l0 + l;
        const f16*  xsp = xs + (b * C + c) * N;
        const float* xp = x  + (b * C + c) * N;
        const float center = (float)xsp[gl];          // k=3 tap
        float lossv[KW], xv[KW];
        float lsum = 0.f;
#pragma unroll
        for (int k = 0; k < KW; ++k) {
            int q = gl + k - 3;
            q = (q < 0) ? -q : ((q >= N) ? (2 * N - 2 - q) : q);   // reflect
            const float v = (float)xsp[q];
            xv[k] = xp[q];
            const float d = fabsf(v - center);
            const float e = __expf(-2.f * d);         // 1-tanh^2 = 4e^{-2d}/(1+e^{-2d})^2
            const float t = 1.f + e;
            const float lo = 4.f * e / (t * t);
            lossv[k] = lo;
            lsum += lo;
        }
        const float alpha = 1.f / lsum;
        unsigned short* pr = phi + l * PLD + c * KW;
#pragma unroll
        for (int k = 0; k < KW; ++k) pr[k] = f2bf(lossv[k] * alpha * xv[k]);
    }
    __syncthreads();

    // ---- phase 2 (MFMA) ----
    const int wv   = tid >> 6;
    const int lane = tid & 63;
    const int quad = lane >> 4;     // k-offset = quad*8
    const int rr   = lane & 15;     // free index within tile
    const int o0   = wv * 32;

    floatx4 acc00 = {0.f, 0.f, 0.f, 0.f}, acc01 = acc00, acc10 = acc00, acc11 = acc00;
    const unsigned short* wrow0 = wb + (o0 + rr) * F + quad * 8;        // A tile 0
    const unsigned short* wrow1 = wrow0 + 16 * F;                       // A tile 1
    const unsigned short* prow0 = phi + rr * PLD + quad * 8;            // B tile 0
    const unsigned short* prow1 = prow0 + 16 * PLD;                     // B tile 1

    for (int s = 0; s < F / 32; ++s) {              // 14 K-steps of 32
        const int f0 = 32 * s;
        const short8 a0 = *(const short8*)(wrow0 + f0);
        const short8 a1 = *(const short8*)(wrow1 + f0);
        const short8 b0 = *(const short8*)(prow0 + f0);
        const short8 b1 = *(const short8*)(prow1 + f0);
        acc00 = __builtin_amdgcn_mfma_f32_16x16x32_bf16(a0, b0, acc00, 0, 0, 0);
        acc01 = __builtin_amdgcn_mfma_f32_16x16x32_bf16(a0, b1, acc01, 0, 0, 0);
        acc10 = __builtin_amdgcn_mfma_f32_16x16x32_bf16(a1, b0, acc10, 0, 0, 0);
        acc11 = __builtin_amdgcn_mfma_f32_16x16x32_bf16(a1, b1, acc11, 0, 0, 0);
    }

    // C/D layout (m89-verified): col = lane&15 (=l within tile), row = quad*4 + reg (=o within tile)
    float* ob = out + (b * CO) * N + l0;
#pragma unroll
    for (int i = 0; i < 4; ++i) {
        const int om = quad * 4 + i;
        ob[(o0 + om) * N      + rr     ] = acc00[i];
        ob[(o0 + om) * N      + 16 + rr] = acc01[i];
        ob[(o0 + 16 + om) * N + rr     ] = acc10[i];
        ob[(o0 + 16 + om) * N + 16 + rr] = acc11[i];
    }
}
} // namespace

extern "C" void kernel_launch(void* const* d_in, const int* in_sizes, int n_in,
                              void* d_out, int out_size, void* d_ws, size_t ws_size,
                              hipStream_t stream)
{
    const float* deep   = (const float*)d_in[0];
    const float* x      = (const float*)d_in[1];
    const float* conv_w = (const float*)d_in[2];
    const float* conv_b = (const float*)d_in[3];
    const float* fc_w   = (const float*)d_in[4];
    float* out = (float*)d_out;

    f16* xs = (f16*)d_ws;                                        // 8 MiB
    unsigned short* wb = (unsigned short*)((char*)d_ws + (8u << 20));  // 112 KiB bf16 fc_w

    hipLaunchKernelGGL(k1, dim3(Bc * C + 56), dim3(256), 0, stream,
                       deep, conv_w, conv_b, fc_w, xs, wb);
    hipLaunchKernelGGL(k2, dim3(N / LT, Bc), dim3(256), 0, stream,
                       xs, x, wb, out);
}